// Round 8
// baseline (289.245 us; speedup 1.0000x reference)
//
#include <hip/hip_runtime.h>
#include <hip/hip_bf16.h>
#include <math.h>

// Problem: B=4, L=2048, D=1024, H=16, KD=64. fp32 in/out; bf16 MFMA inside.

typedef __bf16 bf16x8 __attribute__((ext_vector_type(8)));
typedef float f32x4 __attribute__((ext_vector_type(4)));

__device__ __forceinline__ f32x4 mfma16(bf16x8 a, bf16x8 b, f32x4 c) {
    return __builtin_amdgcn_mfma_f32_16x16x32_bf16(a, b, c, 0, 0, 0);
}

// async global->LDS, 16B per lane. LDS dest = wave-uniform base + lane*16.
__device__ __forceinline__ void async16(const void* g, void* l) {
    __builtin_amdgcn_global_load_lds(
        (const __attribute__((address_space(1))) unsigned int*)g,
        (__attribute__((address_space(3))) unsigned int*)l, 16, 0, 0);
}

// ---------- fp32 -> bf16 convert (vec4) ----------
__global__ void cvt_f32_bf16_v4(const float* __restrict__ in,
                                __hip_bfloat16* __restrict__ out, int n4) {
    int i = blockIdx.x * blockDim.x + threadIdx.x;
    if (i >= n4) return;
    float4 v = ((const float4*)in)[i];
    __hip_bfloat16 t[4];
    t[0] = __float2bfloat16(v.x);
    t[1] = __float2bfloat16(v.y);
    t[2] = __float2bfloat16(v.z);
    t[3] = __float2bfloat16(v.w);
    ((uint2*)out)[i] = *(uint2*)t;
}

// ---------- tiled transpose + convert: W[K][N] f32 -> Wt[N][K] bf16 ----------
__global__ void transpose_cvt(const float* __restrict__ W,
                              __hip_bfloat16* __restrict__ Wt, int K, int N) {
    __shared__ float tile[32][33];
    int tid = threadIdx.x;
    int tx = tid & 31, ty = tid >> 5;
    int n0 = blockIdx.x * 32, k0 = blockIdx.y * 32;
#pragma unroll
    for (int i = 0; i < 4; ++i)
        tile[ty + 8 * i][tx] = W[(size_t)(k0 + ty + 8 * i) * N + n0 + tx];
    __syncthreads();
#pragma unroll
    for (int i = 0; i < 4; ++i)
        Wt[(size_t)(n0 + ty + 8 * i) * K + k0 + tx] =
            __float2bfloat16(tile[tx][ty + 8 * i]);
}

// ---------- GEMM: C[M][N] = A[M][K] * Bt[N][K]^T ----------
// BK=64, global_load_lds staging with XOR bank swizzle (phys group = g^(row&7)).
// MODE 0: fp32 row-major C.  MODE 1: scatter QKV epilogue (bf16, Q pre-scaled).
// MODE 2: split-K over blockIdx.z (K/2 each), fp32 atomicAdd epilogue.
template <int MODE>
__global__ __launch_bounds__(256) void gemm_bf16(
    const __hip_bfloat16* __restrict__ A, const __hip_bfloat16* __restrict__ Bt,
    float* __restrict__ Cf, __hip_bfloat16* __restrict__ Qo,
    __hip_bfloat16* __restrict__ Ko, __hip_bfloat16* __restrict__ Vto, int M,
    int N, int K) {
    __shared__ __hip_bfloat16 As[128 * 64];
    __shared__ __hip_bfloat16 Bs[128 * 64];
    int tid = threadIdx.x;
    int wave = tid >> 6, lane = tid & 63;
    int quad = lane >> 4, l16 = lane & 15;
    int m0 = blockIdx.x * 128, n0 = blockIdx.y * 128;
    int wm = (wave >> 1) * 64, wn = (wave & 1) * 64;
    int srow = lane >> 3;          // staging row within 8-row slab
    int g8 = ((lane & 7) ^ srow) * 8;  // swizzled logical k-group offset
    int swz = (l16 & 7);           // reader swizzle key (row&7 == l16&7)
    int kbeg = 0, kend = K;
    if (MODE == 2) {
        int kh = K >> 1;
        kbeg = blockIdx.z * kh;
        kend = kbeg + kh;
    }
    f32x4 acc[4][4] = {};
    for (int k0 = kbeg; k0 < kend; k0 += 64) {
        __syncthreads();  // previous iteration's LDS reads done
#pragma unroll
        for (int j = 0; j < 4; ++j) {
            int r0 = (j * 4 + wave) * 8;
            async16(&A[(size_t)(m0 + r0 + srow) * K + k0 + g8], &As[r0 * 64]);
            async16(&Bt[(size_t)(n0 + r0 + srow) * K + k0 + g8], &Bs[r0 * 64]);
        }
        __syncthreads();  // drains vmcnt(0): staged data visible
        bf16x8 af[2][4], bfr[2][4];
#pragma unroll
        for (int c = 0; c < 2; ++c) {
            int pg = ((c * 4 + quad) ^ swz) * 8;
#pragma unroll
            for (int i = 0; i < 4; ++i) {
                af[c][i]  = *(const bf16x8*)&As[(wm + i * 16 + l16) * 64 + pg];
                bfr[c][i] = *(const bf16x8*)&Bs[(wn + i * 16 + l16) * 64 + pg];
            }
        }
#pragma unroll
        for (int c = 0; c < 2; ++c)
#pragma unroll
            for (int mi = 0; mi < 4; ++mi)
#pragma unroll
                for (int ni = 0; ni < 4; ++ni)
                    acc[mi][ni] = mfma16(af[c][mi], bfr[c][ni], acc[mi][ni]);
    }
    // epilogue: C/D layout row = quad*4+r, col = lane&15 (m89-verified)
#pragma unroll
    for (int mi = 0; mi < 4; ++mi) {
#pragma unroll
        for (int ni = 0; ni < 4; ++ni) {
            int row0 = m0 + wm + mi * 16 + quad * 4;
            int col = n0 + wn + ni * 16 + l16;
            if (MODE == 0) {
#pragma unroll
                for (int r = 0; r < 4; ++r)
                    Cf[(size_t)(row0 + r) * N + col] = acc[mi][ni][r];
            } else if (MODE == 2) {
#pragma unroll
                for (int r = 0; r < 4; ++r)
                    atomicAdd(&Cf[(size_t)(row0 + r) * N + col],
                              acc[mi][ni][r]);
            } else {
                int which = col >> 10, hd = col & 1023;
                int h = hd >> 6, d = hd & 63;
                if (which == 0) {  // Q: fold 0.125 * log2(e) softmax scale
#pragma unroll
                    for (int r = 0; r < 4; ++r) {
                        int row = row0 + r;
                        int b = row >> 11, l = row & 2047;
                        Qo[(((size_t)b * 16 + h) * 2048 + l) * 64 + d] =
                            __float2bfloat16(acc[mi][ni][r] * 0.18033688011f);
                    }
                } else if (which == 1) {
#pragma unroll
                    for (int r = 0; r < 4; ++r) {
                        int row = row0 + r;
                        int b = row >> 11, l = row & 2047;
                        Ko[(((size_t)b * 16 + h) * 2048 + l) * 64 + d] =
                            __float2bfloat16(acc[mi][ni][r]);
                    }
                } else {  // V^T [bh][64 d][2048 l]: r -> contiguous l, 8B store
                    int b = row0 >> 11, l = row0 & 2047;
                    __hip_bfloat16 t4[4];
#pragma unroll
                    for (int r = 0; r < 4; ++r)
                        t4[r] = __float2bfloat16(acc[mi][ni][r]);
                    *(uint2*)&Vto[(((size_t)b * 16 + h) * 64 + d) * 2048 + l] =
                        *(uint2*)t4;
                }
            }
        }
    }
}

// ---------- flash attention: Q[bh][L][64], K[bh][L][64], Vt[bh][64][L] ----------
// S^T dataflow (r7-verified): S^T = mfma(Kfrag, Qfrag), C col = q, row = key;
// P^T packs 4 consecutive keys -> ds_write_b64; PV B-operand reads 8 keys as
// ds_read_b128. One 128-q-tile per block, 1024 blocks = 4/CU (LDS 36 KB,
// single-buffered K/V; inter-block overlap replaces dbuf). Snake qt mapping:
// the ~4 co-resident blocks per CU sum to ~constant work. XCD-local bh.
__global__ __launch_bounds__(256, 4) void attn_kernel(
    const __hip_bfloat16* __restrict__ Q, const __hip_bfloat16* __restrict__ Kk,
    const __hip_bfloat16* __restrict__ Vt,
    const unsigned char* __restrict__ pm, __hip_bfloat16* __restrict__ Ao) {
    __shared__ __hip_bfloat16 Ks[64 * 64];
    __shared__ __hip_bfloat16 Vs[64 * 64];       // V^T tile [d][key], swizzled
    constexpr int LDK = 72;                      // P[q][key] leading dim
    __shared__ __hip_bfloat16 Ps[4 * 32 * LDK];  // per-wave P [32 q][64 key]
    __shared__ unsigned char pmS[2048];
    __shared__ unsigned char pmAny[32];
    int tid = threadIdx.x;
    int wave = tid >> 6, lane = tid & 63;
    int quad = lane >> 4, l16 = lane & 15;
    int srow = lane >> 3;
    int g8 = ((lane & 7) ^ srow) * 8;
    int swz = (l16 & 7);
    int lin = blockIdx.x;                       // 0..1023
    int bh = (lin & 7) * 8 + ((lin >> 3) & 7);  // 8 bh per XCD (lin%8 = XCD)
    int raw = lin >> 6;                         // 0..15
    int base = (raw & 3) * 2 + (raw >> 3);
    int qt = ((raw >> 2) & 1) ? 15 - base : base;  // snake: CU-sum ~const
    int b = bh >> 4, h = bh & 15;
    const __hip_bfloat16* Qbh = Q + (size_t)bh * 2048 * 64;
    const __hip_bfloat16* Kbh = Kk + (size_t)bh * 2048 * 64;
    const __hip_bfloat16* Vbh = Vt + (size_t)bh * 64 * 2048;
    *(uint2*)&pmS[tid * 8] = *(const uint2*)&pm[b * 2048 + tid * 8];
    __syncthreads();
    if (tid < 32) {  // per-64-key-tile "any padded" flag
        const unsigned long long* q8 = (const unsigned long long*)&pmS[tid * 64];
        unsigned long long v = q8[0] | q8[1] | q8[2] | q8[3] | q8[4] | q8[5] |
                               q8[6] | q8[7];
        pmAny[tid] = v ? 1 : 0;
    }
    __hip_bfloat16* Pw = Ps + wave * 32 * LDK;
    int q0 = qt * 128;
    // Q fragments (B-operand: n = q = l16, k = quad*8+j); scale pre-folded
    bf16x8 qf[2][2];
#pragma unroll
    for (int mi = 0; mi < 2; ++mi) {
        int qrow = q0 + (wave * 2 + mi) * 16 + l16;
        qf[mi][0] = *(const bf16x8*)&Qbh[(size_t)qrow * 64 + quad * 8];
        qf[mi][1] = *(const bf16x8*)&Qbh[(size_t)qrow * 64 + 32 + quad * 8];
    }
    f32x4 ov[2][4] = {};   // O^T: [mi q-block][ni d-block], row=d, col=q
    float lacc[2] = {};    // per-lane row-sum partial for q = l16 (per mi)
    int ktmax = 2 * qt + 1;
    for (int kt = 0; kt <= ktmax; ++kt) {
        __syncthreads();  // all waves done reading Ks/Vs from previous iter
#pragma unroll
        for (int j = 0; j < 2; ++j) {
            int r0 = (j * 4 + wave) * 8;
            async16(&Kbh[((size_t)kt * 64 + r0 + srow) * 64 + g8], &Ks[r0 * 64]);
            async16(&Vbh[(size_t)(r0 + srow) * 2048 + kt * 64 + g8],
                    &Vs[r0 * 64]);
        }
        __syncthreads();  // drains vmcnt(0): staged data visible
        bool anyp = pmAny[kt] != 0;
        bool diag = (kt >= 2 * qt);
        // S^T = K Q^T: per kn, A = K-frag (m=key), B = Q-frag (n=q)
        float pv[2][4][4];
#pragma unroll
        for (int kn = 0; kn < 4; ++kn) {
            int krow = (kn * 16 + l16) * 64;
            bf16x8 kf0 = *(const bf16x8*)&Ks[krow + ((quad ^ swz) * 8)];
            bf16x8 kf1 = *(const bf16x8*)&Ks[krow + (((4 + quad) ^ swz) * 8)];
#pragma unroll
            for (int mi = 0; mi < 2; ++mi) {
                f32x4 s = {};
                s = mfma16(kf0, qf[mi][0], s);
                s = mfma16(kf1, qf[mi][1], s);
#pragma unroll
                for (int r = 0; r < 4; ++r)
                    pv[mi][kn][r] = __builtin_amdgcn_exp2f(s[r]);
            }
        }
        if (anyp) {  // rare: zero padded-key rows
#pragma unroll
            for (int kn = 0; kn < 4; ++kn)
#pragma unroll
                for (int r = 0; r < 4; ++r) {
                    bool pmk = pmS[kt * 64 + kn * 16 + quad * 4 + r] != 0;
#pragma unroll
                    for (int mi = 0; mi < 2; ++mi)
                        if (pmk) pv[mi][kn][r] = 0.f;
                }
        }
        if (diag) {  // causal mask: key > q -> 0
#pragma unroll
            for (int mi = 0; mi < 2; ++mi) {
                int qv = q0 + (wave * 2 + mi) * 16 + l16;
#pragma unroll
                for (int kn = 0; kn < 4; ++kn) {
                    int key = kt * 64 + kn * 16 + quad * 4;
#pragma unroll
                    for (int r = 0; r < 4; ++r)
                        if (key + r > qv) pv[mi][kn][r] = 0.f;
                }
            }
        }
        // row-sum partials (in-lane) and P^T -> LDS as P[q][key] (b64 packs)
#pragma unroll
        for (int mi = 0; mi < 2; ++mi) {
#pragma unroll
            for (int kn = 0; kn < 4; ++kn) {
                lacc[mi] += (pv[mi][kn][0] + pv[mi][kn][1]) +
                            (pv[mi][kn][2] + pv[mi][kn][3]);
                __hip_bfloat162 lo =
                    __float22bfloat162_rn({pv[mi][kn][0], pv[mi][kn][1]});
                __hip_bfloat162 hi =
                    __float22bfloat162_rn({pv[mi][kn][2], pv[mi][kn][3]});
                uint2 w;
                w.x = *(unsigned int*)&lo;
                w.y = *(unsigned int*)&hi;
                *(uint2*)&Pw[(mi * 16 + l16) * LDK + kn * 16 + quad * 4] = w;
            }
        }
        // PV: O^T += V^T P^T (in-wave DS write->read ordering, no barrier)
#pragma unroll
        for (int mi = 0; mi < 2; ++mi) {
#pragma unroll
            for (int hk = 0; hk < 2; ++hk) {
                bf16x8 pf = *(const bf16x8*)&Pw[(mi * 16 + l16) * LDK +
                                                hk * 32 + quad * 8];
#pragma unroll
                for (int ni = 0; ni < 4; ++ni) {
                    int vrow = (ni * 16 + l16) * 64;
                    bf16x8 vf =
                        *(const bf16x8*)&Vs[vrow + (((hk * 4 + quad) ^ swz) * 8)];
                    ov[mi][ni] = mfma16(vf, pf, ov[mi][ni]);
                }
            }
        }
    }
    // epilogue: finish row-sum across quads (lanes l16, 16+l16, ...)
#pragma unroll
    for (int mi = 0; mi < 2; ++mi) {
        float rs = lacc[mi];
        rs += __shfl_xor(rs, 16);
        rs += __shfl_xor(rs, 32);
        float inv = 1.0f / rs;
        int qv = q0 + (wave * 2 + mi) * 16 + l16;
        size_t obase = (size_t)(b * 2048 + qv) * 1024 + h * 64;
#pragma unroll
        for (int ni = 0; ni < 4; ++ni) {
            __hip_bfloat162 lo = __float22bfloat162_rn(
                {ov[mi][ni][0] * inv, ov[mi][ni][1] * inv});
            __hip_bfloat162 hi = __float22bfloat162_rn(
                {ov[mi][ni][2] * inv, ov[mi][ni][3] * inv});
            uint2 w;
            w.x = *(unsigned int*)&lo;
            w.y = *(unsigned int*)&hi;
            *(uint2*)&Ao[obase + ni * 16 + quad * 4] = w;
        }
    }
}

extern "C" void kernel_launch(void* const* d_in, const int* in_sizes, int n_in,
                              void* d_out, int out_size, void* d_ws,
                              size_t ws_size, hipStream_t stream) {
    (void)in_sizes; (void)n_in; (void)out_size; (void)ws_size;
    const float* x = (const float*)d_in[0];
    const unsigned char* pm = (const unsigned char*)d_in[1];
    const float* wqkv = (const float*)d_in[2];
    const float* wout = (const float*)d_in[3];
    float* out = (float*)d_out;

    char* p = (char*)d_ws;
    auto alloc = [&](size_t bytes) {
        char* q = p;
        p += (bytes + 255) & ~(size_t)255;
        return q;
    };
    __hip_bfloat16* xb    = (__hip_bfloat16*)alloc((size_t)8192 * 1024 * 2);
    __hip_bfloat16* wqkvT = (__hip_bfloat16*)alloc((size_t)3072 * 1024 * 2);
    __hip_bfloat16* woutT = (__hip_bfloat16*)alloc((size_t)1024 * 1024 * 2);
    __hip_bfloat16* qws   = (__hip_bfloat16*)alloc((size_t)8192 * 1024 * 2);
    __hip_bfloat16* kws   = (__hip_bfloat16*)alloc((size_t)8192 * 1024 * 2);
    __hip_bfloat16* vtws  = (__hip_bfloat16*)alloc((size_t)8192 * 1024 * 2);
    __hip_bfloat16* attb  = (__hip_bfloat16*)alloc((size_t)8192 * 1024 * 2);

    hipMemsetAsync(out, 0, (size_t)8192 * 1024 * 4, stream);  // split-K target
    cvt_f32_bf16_v4<<<8192, 256, 0, stream>>>(x, xb, 8192 * 1024 / 4);
    transpose_cvt<<<dim3(3072 / 32, 1024 / 32), 256, 0, stream>>>(wqkv, wqkvT,
                                                                  1024, 3072);
    transpose_cvt<<<dim3(1024 / 32, 1024 / 32), 256, 0, stream>>>(wout, woutT,
                                                                  1024, 1024);
    gemm_bf16<1><<<dim3(64, 24), 256, 0, stream>>>(xb, wqkvT, nullptr, qws, kws,
                                                   vtws, 8192, 3072, 1024);
    attn_kernel<<<1024, 256, 0, stream>>>(qws, kws, vtws, pm, attb);
    gemm_bf16<2><<<dim3(64, 8, 2), 256, 0, stream>>>(attb, woutT, out, nullptr,
                                                     nullptr, nullptr, 8192,
                                                     1024, 1024);
}

// Round 9
// 237.445 us; speedup vs baseline: 1.2182x; 1.2182x over previous
//
#include <hip/hip_runtime.h>
#include <hip/hip_bf16.h>
#include <math.h>

// Problem: B=4, L=2048, D=1024, H=16, KD=64. fp32 in/out; bf16 MFMA inside.

typedef __bf16 bf16x8 __attribute__((ext_vector_type(8)));
typedef float f32x4 __attribute__((ext_vector_type(4)));

__device__ __forceinline__ f32x4 mfma16(bf16x8 a, bf16x8 b, f32x4 c) {
    return __builtin_amdgcn_mfma_f32_16x16x32_bf16(a, b, c, 0, 0, 0);
}

// async global->LDS, 16B per lane. LDS dest = wave-uniform base + lane*16.
__device__ __forceinline__ void async16(const void* g, void* l) {
    __builtin_amdgcn_global_load_lds(
        (const __attribute__((address_space(1))) unsigned int*)g,
        (__attribute__((address_space(3))) unsigned int*)l, 16, 0, 0);
}

// ---------- fp32 -> bf16 convert (vec4) ----------
__global__ void cvt_f32_bf16_v4(const float* __restrict__ in,
                                __hip_bfloat16* __restrict__ out, int n4) {
    int i = blockIdx.x * blockDim.x + threadIdx.x;
    if (i >= n4) return;
    float4 v = ((const float4*)in)[i];
    __hip_bfloat16 t[4];
    t[0] = __float2bfloat16(v.x);
    t[1] = __float2bfloat16(v.y);
    t[2] = __float2bfloat16(v.z);
    t[3] = __float2bfloat16(v.w);
    ((uint2*)out)[i] = *(uint2*)t;
}

// ---------- both weight transposes in one launch: W[K][N] -> Wt[N][K] bf16 ----
__global__ void transpose_cvt2(const float* __restrict__ W0,
                               __hip_bfloat16* __restrict__ T0,
                               const float* __restrict__ W1,
                               __hip_bfloat16* __restrict__ T1) {
    const int K = 1024;
    int z = blockIdx.z;
    int N = z ? 1024 : 3072;
    if ((int)blockIdx.x * 32 >= N) return;
    const float* W = z ? W1 : W0;
    __hip_bfloat16* Wt = z ? T1 : T0;
    __shared__ float tile[32][33];
    int tid = threadIdx.x;
    int tx = tid & 31, ty = tid >> 5;
    int n0 = blockIdx.x * 32, k0 = blockIdx.y * 32;
#pragma unroll
    for (int i = 0; i < 4; ++i)
        tile[ty + 8 * i][tx] = W[(size_t)(k0 + ty + 8 * i) * N + n0 + tx];
    __syncthreads();
#pragma unroll
    for (int i = 0; i < 4; ++i)
        Wt[(size_t)(n0 + ty + 8 * i) * K + k0 + tx] =
            __float2bfloat16(tile[tx][ty + 8 * i]);
}

// ---------- GEMM 128x128: C = A * Bt^T, QKV scatter epilogue ----------
// BK=64, global_load_lds staging with XOR bank swizzle (phys group = g^(row&7)).
__global__ __launch_bounds__(256) void gemm_qkv(
    const __hip_bfloat16* __restrict__ A, const __hip_bfloat16* __restrict__ Bt,
    __hip_bfloat16* __restrict__ Qo, __hip_bfloat16* __restrict__ Ko,
    __hip_bfloat16* __restrict__ Vto, int M, int N, int K) {
    __shared__ __hip_bfloat16 As[128 * 64];
    __shared__ __hip_bfloat16 Bs[128 * 64];
    int tid = threadIdx.x;
    int wave = tid >> 6, lane = tid & 63;
    int quad = lane >> 4, l16 = lane & 15;
    int m0 = blockIdx.x * 128, n0 = blockIdx.y * 128;
    int wm = (wave >> 1) * 64, wn = (wave & 1) * 64;
    int srow = lane >> 3;
    int g8 = ((lane & 7) ^ srow) * 8;
    int swz = (l16 & 7);
    f32x4 acc[4][4] = {};
    for (int k0 = 0; k0 < K; k0 += 64) {
        __syncthreads();
#pragma unroll
        for (int j = 0; j < 4; ++j) {
            int r0 = (j * 4 + wave) * 8;
            async16(&A[(size_t)(m0 + r0 + srow) * K + k0 + g8], &As[r0 * 64]);
            async16(&Bt[(size_t)(n0 + r0 + srow) * K + k0 + g8], &Bs[r0 * 64]);
        }
        __syncthreads();
        bf16x8 af[2][4], bfr[2][4];
#pragma unroll
        for (int c = 0; c < 2; ++c) {
            int pg = ((c * 4 + quad) ^ swz) * 8;
#pragma unroll
            for (int i = 0; i < 4; ++i) {
                af[c][i]  = *(const bf16x8*)&As[(wm + i * 16 + l16) * 64 + pg];
                bfr[c][i] = *(const bf16x8*)&Bs[(wn + i * 16 + l16) * 64 + pg];
            }
        }
#pragma unroll
        for (int c = 0; c < 2; ++c)
#pragma unroll
            for (int mi = 0; mi < 4; ++mi)
#pragma unroll
                for (int ni = 0; ni < 4; ++ni)
                    acc[mi][ni] = mfma16(af[c][mi], bfr[c][ni], acc[mi][ni]);
    }
    // epilogue: row = quad*4+r, col = lane&15 (m89-verified)
#pragma unroll
    for (int mi = 0; mi < 4; ++mi) {
#pragma unroll
        for (int ni = 0; ni < 4; ++ni) {
            int row0 = m0 + wm + mi * 16 + quad * 4;
            int col = n0 + wn + ni * 16 + l16;
            int which = col >> 10, hd = col & 1023;
            int h = hd >> 6, d = hd & 63;
            if (which == 0) {  // Q: fold 0.125 * log2(e) softmax scale
#pragma unroll
                for (int r = 0; r < 4; ++r) {
                    int row = row0 + r;
                    int b = row >> 11, l = row & 2047;
                    Qo[(((size_t)b * 16 + h) * 2048 + l) * 64 + d] =
                        __float2bfloat16(acc[mi][ni][r] * 0.18033688011f);
                }
            } else if (which == 1) {
#pragma unroll
                for (int r = 0; r < 4; ++r) {
                    int row = row0 + r;
                    int b = row >> 11, l = row & 2047;
                    Ko[(((size_t)b * 16 + h) * 2048 + l) * 64 + d] =
                        __float2bfloat16(acc[mi][ni][r]);
                }
            } else {  // V^T [bh][64 d][2048 l]: r -> contiguous l, 8B store
                int b = row0 >> 11, l = row0 & 2047;
                __hip_bfloat16 t4[4];
#pragma unroll
                for (int r = 0; r < 4; ++r)
                    t4[r] = __float2bfloat16(acc[mi][ni][r]);
                *(uint2*)&Vto[(((size_t)b * 16 + h) * 64 + d) * 2048 + l] =
                    *(uint2*)t4;
            }
        }
    }
}

// ---------- out-proj GEMM, 128x64 tile: 1024 blocks = 4/CU ----------
// Lighter per-block so the vmcnt-drain barrier is covered by 4 resident
// blocks (the 128x128 out-proj ran at 2 blocks/CU = ~265 TF).
__global__ __launch_bounds__(256) void gemm_out(
    const __hip_bfloat16* __restrict__ A, const __hip_bfloat16* __restrict__ Bt,
    float* __restrict__ Cf, int M, int N, int K) {
    __shared__ __hip_bfloat16 As[128 * 64];
    __shared__ __hip_bfloat16 Bs[64 * 64];
    int tid = threadIdx.x;
    int wave = tid >> 6, lane = tid & 63;
    int quad = lane >> 4, l16 = lane & 15;
    int m0 = blockIdx.x * 128, n0 = blockIdx.y * 64;
    int wm = wave * 32;
    int srow = lane >> 3;
    int g8 = ((lane & 7) ^ srow) * 8;
    int swz = (l16 & 7);
    f32x4 acc[2][4] = {};
    for (int k0 = 0; k0 < K; k0 += 64) {
        __syncthreads();
#pragma unroll
        for (int j = 0; j < 4; ++j) {  // A: 16 slabs of 8 rows, 4 per wave
            int r0 = (wave * 4 + j) * 8;
            async16(&A[(size_t)(m0 + r0 + srow) * K + k0 + g8], &As[r0 * 64]);
        }
#pragma unroll
        for (int j = 0; j < 2; ++j) {  // B: 8 slabs, 2 per wave
            int r0 = (wave * 2 + j) * 8;
            async16(&Bt[(size_t)(n0 + r0 + srow) * K + k0 + g8], &Bs[r0 * 64]);
        }
        __syncthreads();
        bf16x8 af[2][2], bfr[2][4];
#pragma unroll
        for (int c = 0; c < 2; ++c) {
            int pg = ((c * 4 + quad) ^ swz) * 8;
#pragma unroll
            for (int i = 0; i < 2; ++i)
                af[c][i] = *(const bf16x8*)&As[(wm + i * 16 + l16) * 64 + pg];
#pragma unroll
            for (int i = 0; i < 4; ++i)
                bfr[c][i] = *(const bf16x8*)&Bs[(i * 16 + l16) * 64 + pg];
        }
#pragma unroll
        for (int c = 0; c < 2; ++c)
#pragma unroll
            for (int mi = 0; mi < 2; ++mi)
#pragma unroll
                for (int ni = 0; ni < 4; ++ni)
                    acc[mi][ni] = mfma16(af[c][mi], bfr[c][ni], acc[mi][ni]);
    }
#pragma unroll
    for (int mi = 0; mi < 2; ++mi)
#pragma unroll
        for (int ni = 0; ni < 4; ++ni) {
            int row0 = m0 + wm + mi * 16 + quad * 4;
            int col = n0 + ni * 16 + l16;
#pragma unroll
            for (int r = 0; r < 4; ++r)
                Cf[(size_t)(row0 + r) * N + col] = acc[mi][ni][r];
        }
}

// ---------- flash attention (r7-verified best variant, reverted) ----------
// S^T dataflow: S^T = mfma(Kfrag, Qfrag) -> C col = q = l16, row = key.
// P^T packs 4 consecutive keys per lane -> ds_write_b64 into P[q][key];
// PV B-operand reads 8 consecutive keys as ds_read_b128.
// Shell: q-tile 128, paired (15-pr, pr) = 34 iters/block, 512 blocks,
// XCD-local bh, K/V double-buffered via global_load_lds.
__global__ __launch_bounds__(256, 2) void attn_kernel(
    const __hip_bfloat16* __restrict__ Q, const __hip_bfloat16* __restrict__ Kk,
    const __hip_bfloat16* __restrict__ Vt,
    const unsigned char* __restrict__ pm, __hip_bfloat16* __restrict__ Ao) {
    __shared__ __hip_bfloat16 Ks[2 * 64 * 64];
    __shared__ __hip_bfloat16 Vs[2 * 64 * 64];   // V^T tiles [d][key], swizzled
    constexpr int LDK = 72;                      // P[q][key] leading dim
    __shared__ __hip_bfloat16 Ps[4 * 32 * LDK];  // per-wave P [32 q][64 key]
    __shared__ unsigned char pmS[2048];
    __shared__ unsigned char pmAny[32];
    int tid = threadIdx.x;
    int wave = tid >> 6, lane = tid & 63;
    int quad = lane >> 4, l16 = lane & 15;
    int srow = lane >> 3;
    int g8 = ((lane & 7) ^ srow) * 8;
    int swz = (l16 & 7);
    int lin = blockIdx.x;                       // 0..511
    int bh = (lin & 7) * 8 + ((lin >> 3) & 7);  // 8 bh per XCD (lin%8 = XCD)
    int pr = lin >> 6;                          // 0..7: q-tile pair id
    int b = bh >> 4, h = bh & 15;
    const __hip_bfloat16* Qbh = Q + (size_t)bh * 2048 * 64;
    const __hip_bfloat16* Kbh = Kk + (size_t)bh * 2048 * 64;
    const __hip_bfloat16* Vbh = Vt + (size_t)bh * 64 * 2048;
    *(uint2*)&pmS[tid * 8] = *(const uint2*)&pm[b * 2048 + tid * 8];
    __syncthreads();
    if (tid < 32) {  // per-64-key-tile "any padded" flag
        const unsigned long long* q8 = (const unsigned long long*)&pmS[tid * 64];
        unsigned long long v = q8[0] | q8[1] | q8[2] | q8[3] | q8[4] | q8[5] |
                               q8[6] | q8[7];
        pmAny[tid] = v ? 1 : 0;
    }
    __hip_bfloat16* Pw = Ps + wave * 32 * LDK;

    auto stage = [&](int kt, int buf) {
#pragma unroll
        for (int j = 0; j < 2; ++j) {
            int r0 = (j * 4 + wave) * 8;
            async16(&Kbh[((size_t)kt * 64 + r0 + srow) * 64 + g8],
                    &Ks[buf * 4096 + r0 * 64]);
            async16(&Vbh[(size_t)(r0 + srow) * 2048 + kt * 64 + g8],
                    &Vs[buf * 4096 + r0 * 64]);
        }
    };

#pragma unroll
    for (int ph = 0; ph < 2; ++ph) {
        int qt = ph ? pr : 15 - pr;  // pair sums to 34 iterations: balanced
        int q0 = qt * 128;
        // Q fragments (B-operand: n = q = l16, k = quad*8+j); scale pre-folded
        bf16x8 qf[2][2];
#pragma unroll
        for (int mi = 0; mi < 2; ++mi) {
            int qrow = q0 + (wave * 2 + mi) * 16 + l16;
            qf[mi][0] = *(const bf16x8*)&Qbh[(size_t)qrow * 64 + quad * 8];
            qf[mi][1] = *(const bf16x8*)&Qbh[(size_t)qrow * 64 + 32 + quad * 8];
        }
        f32x4 ov[2][4] = {};   // O^T: [mi q-block][ni d-block], row=d, col=q
        float lacc[2] = {};    // per-lane row-sum partial for q = l16 (per mi)
        int ktmax = 2 * qt + 1;
        stage(0, 0);
        for (int kt = 0; kt <= ktmax; ++kt) {
            int cur = kt & 1;
            __syncthreads();  // drains vmcnt: buf[cur] staged; prev reads done
            if (kt < ktmax) stage(kt + 1, cur ^ 1);  // overlaps compute below
            const __hip_bfloat16* Kc = &Ks[cur * 4096];
            const __hip_bfloat16* Vc = &Vs[cur * 4096];
            bool anyp = pmAny[kt] != 0;
            bool diag = (kt >= 2 * qt);
            // S^T = K Q^T: per kn, A = K-frag (m=key), B = Q-frag (n=q)
            float pv[2][4][4];
#pragma unroll
            for (int kn = 0; kn < 4; ++kn) {
                int krow = (kn * 16 + l16) * 64;
                bf16x8 kf0 = *(const bf16x8*)&Kc[krow + ((quad ^ swz) * 8)];
                bf16x8 kf1 = *(const bf16x8*)&Kc[krow + (((4 + quad) ^ swz) * 8)];
#pragma unroll
                for (int mi = 0; mi < 2; ++mi) {
                    f32x4 s = {};
                    s = mfma16(kf0, qf[mi][0], s);
                    s = mfma16(kf1, qf[mi][1], s);
#pragma unroll
                    for (int r = 0; r < 4; ++r)
                        pv[mi][kn][r] = __builtin_amdgcn_exp2f(s[r]);
                }
            }
            if (anyp) {  // rare: zero padded-key rows
#pragma unroll
                for (int kn = 0; kn < 4; ++kn)
#pragma unroll
                    for (int r = 0; r < 4; ++r) {
                        bool pmk = pmS[kt * 64 + kn * 16 + quad * 4 + r] != 0;
#pragma unroll
                        for (int mi = 0; mi < 2; ++mi)
                            if (pmk) pv[mi][kn][r] = 0.f;
                    }
            }
            if (diag) {  // causal mask: key > q -> 0
#pragma unroll
                for (int mi = 0; mi < 2; ++mi) {
                    int qv = q0 + (wave * 2 + mi) * 16 + l16;
#pragma unroll
                    for (int kn = 0; kn < 4; ++kn) {
                        int key = kt * 64 + kn * 16 + quad * 4;
#pragma unroll
                        for (int r = 0; r < 4; ++r)
                            if (key + r > qv) pv[mi][kn][r] = 0.f;
                    }
                }
            }
            // row-sum partials (in-lane) and P^T -> LDS as P[q][key] (b64)
#pragma unroll
            for (int mi = 0; mi < 2; ++mi) {
#pragma unroll
                for (int kn = 0; kn < 4; ++kn) {
                    lacc[mi] += (pv[mi][kn][0] + pv[mi][kn][1]) +
                                (pv[mi][kn][2] + pv[mi][kn][3]);
                    __hip_bfloat162 lo =
                        __float22bfloat162_rn({pv[mi][kn][0], pv[mi][kn][1]});
                    __hip_bfloat162 hi =
                        __float22bfloat162_rn({pv[mi][kn][2], pv[mi][kn][3]});
                    uint2 w;
                    w.x = *(unsigned int*)&lo;
                    w.y = *(unsigned int*)&hi;
                    *(uint2*)&Pw[(mi * 16 + l16) * LDK + kn * 16 + quad * 4] = w;
                }
            }
            // PV: O^T += V^T P^T (in-wave DS write->read ordering, no barrier)
#pragma unroll
            for (int mi = 0; mi < 2; ++mi) {
#pragma unroll
                for (int hk = 0; hk < 2; ++hk) {
                    bf16x8 pf = *(const bf16x8*)&Pw[(mi * 16 + l16) * LDK +
                                                    hk * 32 + quad * 8];
#pragma unroll
                    for (int ni = 0; ni < 4; ++ni) {
                        int vrow = (ni * 16 + l16) * 64;
                        bf16x8 vf = *(const bf16x8*)&Vc[vrow +
                                                        (((hk * 4 + quad) ^ swz) *
                                                         8)];
                        ov[mi][ni] = mfma16(vf, pf, ov[mi][ni]);
                    }
                }
            }
        }
        // epilogue: finish row-sum across quads (lanes l16, 16+l16, ...)
#pragma unroll
        for (int mi = 0; mi < 2; ++mi) {
            float rs = lacc[mi];
            rs += __shfl_xor(rs, 16);
            rs += __shfl_xor(rs, 32);
            float inv = 1.0f / rs;
            int qv = q0 + (wave * 2 + mi) * 16 + l16;
            size_t obase = (size_t)(b * 2048 + qv) * 1024 + h * 64;
#pragma unroll
            for (int ni = 0; ni < 4; ++ni) {
                __hip_bfloat162 lo = __float22bfloat162_rn(
                    {ov[mi][ni][0] * inv, ov[mi][ni][1] * inv});
                __hip_bfloat162 hi = __float22bfloat162_rn(
                    {ov[mi][ni][2] * inv, ov[mi][ni][3] * inv});
                uint2 w;
                w.x = *(unsigned int*)&lo;
                w.y = *(unsigned int*)&hi;
                *(uint2*)&Ao[obase + ni * 16 + quad * 4] = w;
            }
        }
        lacc[0] = lacc[1] = 0.f;
    }
}

extern "C" void kernel_launch(void* const* d_in, const int* in_sizes, int n_in,
                              void* d_out, int out_size, void* d_ws,
                              size_t ws_size, hipStream_t stream) {
    (void)in_sizes; (void)n_in; (void)out_size; (void)ws_size;
    const float* x = (const float*)d_in[0];
    const unsigned char* pm = (const unsigned char*)d_in[1];
    const float* wqkv = (const float*)d_in[2];
    const float* wout = (const float*)d_in[3];
    float* out = (float*)d_out;

    char* p = (char*)d_ws;
    auto alloc = [&](size_t bytes) {
        char* q = p;
        p += (bytes + 255) & ~(size_t)255;
        return q;
    };
    __hip_bfloat16* xb    = (__hip_bfloat16*)alloc((size_t)8192 * 1024 * 2);
    __hip_bfloat16* wqkvT = (__hip_bfloat16*)alloc((size_t)3072 * 1024 * 2);
    __hip_bfloat16* woutT = (__hip_bfloat16*)alloc((size_t)1024 * 1024 * 2);
    __hip_bfloat16* qws   = (__hip_bfloat16*)alloc((size_t)8192 * 1024 * 2);
    __hip_bfloat16* kws   = (__hip_bfloat16*)alloc((size_t)8192 * 1024 * 2);
    __hip_bfloat16* vtws  = (__hip_bfloat16*)alloc((size_t)8192 * 1024 * 2);
    __hip_bfloat16* attb  = (__hip_bfloat16*)alloc((size_t)8192 * 1024 * 2);

    cvt_f32_bf16_v4<<<8192, 256, 0, stream>>>(x, xb, 8192 * 1024 / 4);
    transpose_cvt2<<<dim3(96, 32, 2), 256, 0, stream>>>(wqkv, wqkvT, wout,
                                                        woutT);
    gemm_qkv<<<dim3(64, 24), 256, 0, stream>>>(xb, wqkvT, qws, kws, vtws, 8192,
                                               3072, 1024);
    attn_kernel<<<512, 256, 0, stream>>>(qws, kws, vtws, pm, attb);
    gemm_out<<<dim3(64, 16), 256, 0, stream>>>(attb, woutT, out, 8192, 1024,
                                               1024);
}